// Round 1
// baseline (400.801 us; speedup 1.0000x reference)
//
#include <hip/hip_runtime.h>
#include <hip/hip_bf16.h>
#include <math.h>

#define BDIM 32
#define HD   1024
#define SD   128
#define VD   32000

typedef __attribute__((ext_vector_type(8))) short short8;
typedef __attribute__((ext_vector_type(4))) float floatx4;

__device__ __forceinline__ short f2bf(float f) {
    unsigned u = __builtin_bit_cast(unsigned, f);
    u += 0x7FFFu + ((u >> 16) & 1u);
    return (short)(u >> 16);
}
__device__ __forceinline__ float bf2f(short h) {
    unsigned u = ((unsigned)(unsigned short)h) << 16;
    return __builtin_bit_cast(float, u);
}

// swizzled layout for the B-operand (the [32,K] activation matrix):
// value A[b][k] lives at ((t*2+mt)*64 + q*16 + i)*8 + j
// with t=k/32, q=(k%32)/8, j=k%8, mt=b/16, i=b%16.
// Then lane l of a wave loads short8 at ((t*2+hb)*64+l) and element j is
// B[k = t*32 + (l>>4)*8 + j][b = hb*16 + (l&15)]  -- the MFMA B-frag.
__device__ __forceinline__ size_t swz_idx(int b, int k) {
    int t = k >> 5, q = (k & 31) >> 3, j = k & 7;
    int mt = b >> 4, i = b & 15;
    return ((size_t)(((t * 2 + mt) * 64) + q * 16 + i) << 3) + j;
}

#define MFMA(a, b, c) __builtin_amdgcn_mfma_f32_16x16x32_bf16(a, b, c, 0, 0, 0)

// ---------------------------------------------------------------------------
// prep0: prefill bias into atomic-accumulated outputs + swizzle x0/h0 (hi/lo)
// ---------------------------------------------------------------------------
__global__ __launch_bounds__(256) void prep0(
    const float* __restrict__ x0, const float* __restrict__ h0,
    const float* __restrict__ b_ih, const float* __restrict__ b_hh,
    const float* __restrict__ b_comb,
    float* __restrict__ xg, float* __restrict__ hg,
    float* __restrict__ v, float* __restrict__ comb,
    short* __restrict__ x0h, short* __restrict__ x0l,
    short* __restrict__ h0h, short* __restrict__ h0l)
{
    int idx = blockIdx.x * 256 + threadIdx.x;
    if (idx < 98304) { xg[idx] = b_ih[idx % 3072]; return; }
    idx -= 98304;
    if (idx < 98304) { hg[idx] = b_hh[idx % 3072]; return; }
    idx -= 98304;
    if (idx < 32768) { v[idx] = 0.f; return; }
    idx -= 32768;
    if (idx < 32768) { comb[idx] = b_comb[idx & 1023]; return; }
    idx -= 32768;
    if (idx < 32768) {
        int b = idx >> 10, k = idx & 1023;
        float xv = x0[idx]; short hh = f2bf(xv);
        size_t d = swz_idx(b, k);
        x0h[d] = hh; x0l[d] = f2bf(xv - bf2f(hh));
        return;
    }
    idx -= 32768;
    {
        int b = idx >> 10, k = idx & 1023;
        float xv = h0[idx]; short hh = f2bf(xv);
        size_t d = swz_idx(b, k);
        h0h[d] = hh; h0l[d] = f2bf(xv - bf2f(hh));
    }
}

// ---------------------------------------------------------------------------
// gemm_bt: out[b][n] (+)= sum_k A[b][k] * W[n][k]   (A given bf16-swizzled)
// block = 256 (4 waves), each wave does a 16-row W tile x all 32 b.
// SPLIT: hi/lo bf16 on both operands (3-term product) for fp32-like accuracy.
// ---------------------------------------------------------------------------
template<int ATOMIC, int SPLIT, int KCHUNK>
__global__ __launch_bounds__(256) void gemm_bt(
    const short* __restrict__ bhi, const short* __restrict__ blo,
    const float* __restrict__ W, const float* __restrict__ bias,
    float* __restrict__ out, int N, int K)
{
    int tid = threadIdx.x;
    int w = tid >> 6, l = tid & 63;
    int i = l & 15, q = l >> 4;
    int n0 = blockIdx.x * 64 + w * 16;
    int k0 = blockIdx.y * KCHUNK;
    const float* wrow = W + (size_t)(n0 + i) * K + q * 8;
    const short8* bph = (const short8*)bhi + l;
    const short8* bpl = (const short8*)blo + l;

    floatx4 acc0 = {0.f, 0.f, 0.f, 0.f};
    floatx4 acc1 = {0.f, 0.f, 0.f, 0.f};

#pragma unroll 2
    for (int kk = k0; kk < k0 + KCHUNK; kk += 32) {
        float4 w0 = *(const float4*)(wrow + kk);
        float4 w1 = *(const float4*)(wrow + kk + 4);
        float wf[8] = {w0.x, w0.y, w0.z, w0.w, w1.x, w1.y, w1.z, w1.w};
        short8 ahi, alo;
#pragma unroll
        for (int j = 0; j < 8; ++j) {
            short hh = f2bf(wf[j]);
            ahi[j] = hh;
            if (SPLIT) alo[j] = f2bf(wf[j] - bf2f(hh));
        }
        int t2 = (kk >> 5) * 2;
        short8 b0 = bph[(size_t)t2 * 64];
        short8 b1 = bph[(size_t)(t2 + 1) * 64];
        acc0 = MFMA(ahi, b0, acc0);
        acc1 = MFMA(ahi, b1, acc1);
        if (SPLIT) {
            short8 l0 = bpl[(size_t)t2 * 64];
            short8 l1 = bpl[(size_t)(t2 + 1) * 64];
            acc0 = MFMA(ahi, l0, acc0);
            acc1 = MFMA(ahi, l1, acc1);
            acc0 = MFMA(alo, b0, acc0);
            acc1 = MFMA(alo, b1, acc1);
        }
    }

    // epilogue: transpose D (row = W-row offset, col = b) through LDS so the
    // global write is contiguous float4 per b-row.
    __shared__ float lds[4][32][17];
#pragma unroll
    for (int r = 0; r < 4; ++r) {
        lds[w][i][q * 4 + r]      = acc0[r];
        lds[w][i + 16][q * 4 + r] = acc1[r];
    }
    __syncthreads();
    int b = l >> 1, hf = l & 1;
    float vo[8];
#pragma unroll
    for (int t = 0; t < 8; ++t) vo[t] = lds[w][b][hf * 8 + t];
    size_t obase = (size_t)b * N + n0 + hf * 8;
    if (ATOMIC) {
#pragma unroll
        for (int t = 0; t < 8; ++t) atomicAdd(out + obase + t, vo[t]);
    } else {
        const float4* bp4 = (const float4*)(bias + n0 + hf * 8);
        float4 bb0 = bp4[0], bb1 = bp4[1];
        float4 o0 = {vo[0] + bb0.x, vo[1] + bb0.y, vo[2] + bb0.z, vo[3] + bb0.w};
        float4 o1 = {vo[4] + bb1.x, vo[5] + bb1.y, vo[6] + bb1.z, vo[7] + bb1.w};
        float4* op = (float4*)(out + obase);
        op[0] = o0; op[1] = o1;
    }
}

// ---------------------------------------------------------------------------
// GRU gate fusion -> dec, written directly as hi/lo swizzled bf16
// ---------------------------------------------------------------------------
__global__ __launch_bounds__(256) void gru_gate(
    const float* __restrict__ xg, const float* __restrict__ hg,
    const float* __restrict__ h0, short* __restrict__ dh, short* __restrict__ dl)
{
    int idx = blockIdx.x * 256 + threadIdx.x;   // 32*1024
    int b = idx >> 10, h = idx & 1023;
    const float* xp = xg + (size_t)b * 3072 + h;
    const float* hp = hg + (size_t)b * 3072 + h;
    float r = 1.f / (1.f + expf(-(xp[0] + hp[0])));
    float z = 1.f / (1.f + expf(-(xp[1024] + hp[1024])));
    float n = tanhf(xp[2048] + r * hp[2048]);
    float dec = (1.f - z) * n + z * h0[idx];
    short hh = f2bf(dec);
    size_t d = swz_idx(b, h);
    dh[d] = hh; dl[d] = f2bf(dec - bf2f(hh));
}

// ---------------------------------------------------------------------------
// v[b][e] = sum_h dec[b][h] * W_attn[h][1024+e]  (A-operand column-strided)
// ---------------------------------------------------------------------------
template<int KCHUNK>
__global__ __launch_bounds__(256) void gemm_attn(
    const short* __restrict__ dhi, const short* __restrict__ dlo,
    const float* __restrict__ Wa, float* __restrict__ v)
{
    int tid = threadIdx.x, w = tid >> 6, l = tid & 63;
    int i = l & 15, q = l >> 4;
    int e0 = blockIdx.x * 64 + w * 16;
    int k0 = blockIdx.y * KCHUNK;
    const float* col = Wa + 1024 + e0 + i;   // row stride 2048
    const short8* bph = (const short8*)dhi + l;
    const short8* bpl = (const short8*)dlo + l;
    floatx4 acc0 = {0.f, 0.f, 0.f, 0.f};
    floatx4 acc1 = {0.f, 0.f, 0.f, 0.f};
    for (int kk = k0; kk < k0 + KCHUNK; kk += 32) {
        short8 ahi, alo;
#pragma unroll
        for (int j = 0; j < 8; ++j) {
            float xv = col[(size_t)(kk + q * 8 + j) * 2048];
            short hh = f2bf(xv);
            ahi[j] = hh; alo[j] = f2bf(xv - bf2f(hh));
        }
        int t2 = (kk >> 5) * 2;
        short8 b0 = bph[(size_t)t2 * 64];
        short8 b1 = bph[(size_t)(t2 + 1) * 64];
        short8 l0 = bpl[(size_t)t2 * 64];
        short8 l1 = bpl[(size_t)(t2 + 1) * 64];
        acc0 = MFMA(ahi, b0, acc0);
        acc1 = MFMA(ahi, b1, acc1);
        acc0 = MFMA(ahi, l0, acc0);
        acc1 = MFMA(ahi, l1, acc1);
        acc0 = MFMA(alo, b0, acc0);
        acc1 = MFMA(alo, b1, acc1);
    }
    // D[row = e-offset][col = b]
#pragma unroll
    for (int r = 0; r < 4; ++r) {
        atomicAdd(v + (size_t)i * 1024 + e0 + q * 4 + r, acc0[r]);
        atomicAdd(v + (size_t)(i + 16) * 1024 + e0 + q * 4 + r, acc1[r]);
    }
}

// ---------------------------------------------------------------------------
// scores[b][s] = v[b] . enc[s][b]   (one wave per (s,b))
// ---------------------------------------------------------------------------
__global__ __launch_bounds__(256) void scores_k(
    const float* __restrict__ v, const float* __restrict__ enc,
    float* __restrict__ sc)
{
    int w = threadIdx.x >> 6, l = threadIdx.x & 63;
    int id = blockIdx.x * 4 + w;          // 0..4095
    int s = id >> 5, b = id & 31;
    const float4* ep = (const float4*)(enc + ((size_t)s * BDIM + b) * 1024);
    const float4* vp = (const float4*)(v + (size_t)b * 1024);
    float acc = 0.f;
#pragma unroll
    for (int c = 0; c < 4; ++c) {
        float4 e4 = ep[l + 64 * c];
        float4 v4 = vp[l + 64 * c];
        acc += e4.x * v4.x + e4.y * v4.y + e4.z * v4.z + e4.w * v4.w;
    }
    for (int o = 32; o; o >>= 1) acc += __shfl_down(acc, o);
    if (l == 0) sc[b * SD + s] = acc;
}

__global__ void softmax_k(const float* __restrict__ sc,
                          float* __restrict__ aw, float* __restrict__ aw_out)
{
    int b = blockIdx.x, s = threadIdx.x;   // 128 threads
    int w = s >> 6, l = s & 63;
    float x = sc[b * SD + s];
    __shared__ float lm[2], ls[2];
    float m = x;
    for (int o = 32; o; o >>= 1) m = fmaxf(m, __shfl_down(m, o));
    if (l == 0) lm[w] = m;
    __syncthreads();
    float M = fmaxf(lm[0], lm[1]);
    float e = expf(x - M);
    float su = e;
    for (int o = 32; o; o >>= 1) su += __shfl_down(su, o);
    if (l == 0) ls[w] = su;
    __syncthreads();
    float r = e / (ls[0] + ls[1]);
    aw[b * SD + s] = r;
    aw_out[b * SD + s] = r;
}

__global__ __launch_bounds__(256) void context_k(
    const float* __restrict__ aw, const float* __restrict__ enc,
    float* __restrict__ ctx)
{
    int b = blockIdx.y;
    int e = blockIdx.x * 256 + threadIdx.x;
    __shared__ float a[SD];
    if (threadIdx.x < SD) a[threadIdx.x] = aw[b * SD + threadIdx.x];
    __syncthreads();
    const float* p = enc + (size_t)b * 1024 + e;
    float acc = 0.f;
#pragma unroll 4
    for (int s = 0; s < SD; ++s) acc += a[s] * p[(size_t)s * (BDIM * 1024)];
    ctx[(size_t)b * 1024 + e] = acc;
}

__global__ __launch_bounds__(256) void cat_prep(
    const float* __restrict__ x0, const float* __restrict__ ctx,
    short* __restrict__ ch)
{
    int idx = blockIdx.x * 256 + threadIdx.x;   // 32*2048
    int b = idx >> 11, k = idx & 2047;
    float xv = (k < 1024) ? x0[(b << 10) + k] : ctx[(b << 10) + (k & 1023)];
    ch[swz_idx(b, k)] = f2bf(xv);
}

__global__ __launch_bounds__(256) void comb_prep(
    const float* __restrict__ comb, short* __restrict__ ch)
{
    int idx = blockIdx.x * 256 + threadIdx.x;   // 32*1024
    int b = idx >> 10, k = idx & 1023;
    ch[swz_idx(b, k)] = f2bf(comb[idx]);
}

__global__ __launch_bounds__(256) void lse_k(
    const float* __restrict__ logits, float* __restrict__ lse)
{
    int b = blockIdx.x, t = threadIdx.x;
    int w = t >> 6, l = t & 63;
    const float* row = logits + (size_t)b * VD;
    float m = -3.4e38f;
    for (int vv = t; vv < VD; vv += 256) m = fmaxf(m, row[vv]);
    __shared__ float red[4], red2[4];
    for (int o = 32; o; o >>= 1) m = fmaxf(m, __shfl_down(m, o));
    if (l == 0) red[w] = m;
    __syncthreads();
    float M = fmaxf(fmaxf(red[0], red[1]), fmaxf(red[2], red[3]));
    float su = 0.f;
    for (int vv = t; vv < VD; vv += 256) su += expf(row[vv] - M);
    for (int o = 32; o; o >>= 1) su += __shfl_down(su, o);
    if (l == 0) red2[w] = su;
    __syncthreads();
    if (t == 0) lse[b] = M + logf(red2[0] + red2[1] + red2[2] + red2[3]);
}

__global__ __launch_bounds__(256) void final_k(
    const float* __restrict__ logits, const float* __restrict__ lse,
    float* __restrict__ out)
{
    int b = blockIdx.y;
    int vv = blockIdx.x * 256 + threadIdx.x;
    size_t o = (size_t)b * VD + vv;
    out[o] = logits[o] - lse[b];
}

// ---------------------------------------------------------------------------
extern "C" void kernel_launch(void* const* d_in, const int* in_sizes, int n_in,
                              void* d_out, int out_size, void* d_ws, size_t ws_size,
                              hipStream_t stream) {
    const float* x      = (const float*)d_in[0];
    const float* enc    = (const float*)d_in[1];
    const float* hid    = (const float*)d_in[2];
    const float* W_ih   = (const float*)d_in[3];
    const float* W_hh   = (const float*)d_in[4];
    const float* b_ih   = (const float*)d_in[5];
    const float* b_hh   = (const float*)d_in[6];
    const float* W_attn = (const float*)d_in[7];
    const float* W_comb = (const float*)d_in[9];
    const float* b_comb = (const float*)d_in[10];
    const float* W_out  = (const float*)d_in[11];
    const float* b_out  = (const float*)d_in[12];
    float* out = (float*)d_out;

    float* wsf    = (float*)d_ws;
    float* xg     = wsf;                 // 98304
    float* hg     = xg + 98304;          // 98304
    float* v      = hg + 98304;          // 32768
    float* comb   = v + 32768;           // 32768
    float* sc     = comb + 32768;        // 4096
    float* aw     = sc + 4096;           // 4096
    float* ctx    = aw + 4096;           // 32768
    float* lse    = ctx + 32768;         // 32
    float* logits = lse + 32;            // 1024000
    short* x0h    = (short*)(logits + 1024000);
    short* x0l    = x0h + 32768;
    short* h0h    = x0l + 32768;
    short* h0l    = h0h + 32768;
    short* dh     = h0l + 32768;
    short* dl     = dh + 32768;
    short* cath   = dl + 32768;          // 65536
    short* combh  = cath + 65536;        // 32768

    prep0<<<1280, 256, 0, stream>>>(x, hid, b_ih, b_hh, b_comb,
                                    xg, hg, v, comb, x0h, x0l, h0h, h0l);
    gemm_bt<1, 1, 512><<<dim3(48, 2), 256, 0, stream>>>(
        x0h, x0l, W_ih, nullptr, xg, 3072, 1024);
    gemm_bt<1, 1, 512><<<dim3(48, 2), 256, 0, stream>>>(
        h0h, h0l, W_hh, nullptr, hg, 3072, 1024);
    gru_gate<<<128, 256, 0, stream>>>(xg, hg, hid, dh, dl);
    gemm_attn<128><<<dim3(16, 8), 256, 0, stream>>>(dh, dl, W_attn, v);
    scores_k<<<1024, 256, 0, stream>>>(v, enc, sc);
    softmax_k<<<32, 128, 0, stream>>>(sc, aw, out + 1024000);
    context_k<<<dim3(4, 32), 256, 0, stream>>>(aw, enc, ctx);
    cat_prep<<<256, 256, 0, stream>>>(x, ctx, cath);
    gemm_bt<1, 0, 256><<<dim3(16, 8), 256, 0, stream>>>(
        cath, nullptr, W_comb, nullptr, comb, 1024, 2048);
    comb_prep<<<128, 256, 0, stream>>>(comb, combh);
    gemm_bt<0, 0, 1024><<<dim3(500, 1), 256, 0, stream>>>(
        combh, nullptr, W_out, b_out, logits, 32000, 1024);
    lse_k<<<32, 256, 0, stream>>>(logits, lse);
    final_k<<<dim3(125, 32), 256, 0, stream>>>(logits, lse, out);
}

// Round 2
// 316.666 us; speedup vs baseline: 1.2657x; 1.2657x over previous
//
#include <hip/hip_runtime.h>
#include <hip/hip_bf16.h>
#include <math.h>

#define BDIM 32
#define HD   1024
#define SD   128
#define VD   32000

typedef __attribute__((ext_vector_type(8))) short short8;
typedef __attribute__((ext_vector_type(4))) float floatx4;

__device__ __forceinline__ short f2bf(float f) {
    unsigned u = __builtin_bit_cast(unsigned, f);
    u += 0x7FFFu + ((u >> 16) & 1u);
    return (short)(u >> 16);
}
__device__ __forceinline__ float bf2f(short h) {
    unsigned u = ((unsigned)(unsigned short)h) << 16;
    return __builtin_bit_cast(float, u);
}
// pack two fp32 -> one dword of two bf16 (round-half-up; ~2.5 VALU/elt)
__device__ __forceinline__ unsigned pack2(float a, float b) {
    unsigned ua = __builtin_bit_cast(unsigned, a) + 0x8000u;
    unsigned ub = __builtin_bit_cast(unsigned, b) + 0x8000u;
    return (ub & 0xffff0000u) | (ua >> 16);
}

// swizzled layout for MFMA operand fragments of the [32,K] activation:
// element A[b][k] at ((t*2+mt)*64 + q*16 + i)*8 + j
// t=k/32, q=(k%32)/8, j=k%8, mt=b/16, i=b%16.
// lane l reading short8 at ((t*2+mt)*64+l) gets element j =
// M[k=t*32+(l>>4)*8+j][b=mt*16+(l&15)] -- valid as both A-frag and B-frag.
__device__ __forceinline__ size_t swz_idx(int b, int k) {
    int t = k >> 5, q = (k & 31) >> 3, j = k & 7;
    int mt = b >> 4, i = b & 15;
    return ((size_t)(((t * 2 + mt) * 64) + q * 16 + i) << 3) + j;
}

#define MFMA(a, b, c) __builtin_amdgcn_mfma_f32_16x16x32_bf16(a, b, c, 0, 0, 0)

// ---------------------------------------------------------------------------
// prep0: bias prefills + zero inits + swizzle x0/h0 (hi/lo) + cat first half
// ---------------------------------------------------------------------------
__global__ __launch_bounds__(256) void prep0(
    const float* __restrict__ x0, const float* __restrict__ h0,
    const float* __restrict__ b_ih, const float* __restrict__ b_hh,
    const float* __restrict__ b_comb,
    float* __restrict__ xg, float* __restrict__ hg,
    float* __restrict__ v, float* __restrict__ sexp,
    float* __restrict__ comb,
    short* __restrict__ x0h, short* __restrict__ x0l,
    short* __restrict__ h0h, short* __restrict__ h0l,
    short* __restrict__ cath)
{
    int idx = blockIdx.x * 256 + threadIdx.x;
    if (idx < 98304) { xg[idx] = b_ih[idx % 3072]; return; }
    idx -= 98304;
    if (idx < 98304) { hg[idx] = b_hh[idx % 3072]; return; }
    idx -= 98304;
    if (idx < 32768) { v[idx] = 0.f; return; }
    idx -= 32768;
    if (idx < 32) { sexp[idx] = 0.f; return; }
    idx -= 32;
    if (idx < 32768) { comb[idx] = b_comb[idx & 1023]; return; }
    idx -= 32768;
    if (idx < 32768) {
        int b = idx >> 10, k = idx & 1023;
        float xv = x0[idx]; short hh = f2bf(xv);
        size_t d = swz_idx(b, k);
        x0h[d] = hh; x0l[d] = f2bf(xv - bf2f(hh)); cath[d] = hh;
        return;
    }
    idx -= 32768;
    if (idx < 32768) {
        int b = idx >> 10, k = idx & 1023;
        float xv = h0[idx]; short hh = f2bf(xv);
        size_t d = swz_idx(b, k);
        h0h[d] = hh; h0l[d] = f2bf(xv - bf2f(hh));
    }
}

// ---------------------------------------------------------------------------
// gemm_bt body: out[b][n] (+)= sum_k act[b][k] * W[n][k]  (act bf16-swizzled)
// ---------------------------------------------------------------------------
template<int ATOMIC, int SPLIT, int KCHUNK>
__device__ __forceinline__ void gemm_bt_body(
    const short* __restrict__ bhi, const short* __restrict__ blo,
    const float* __restrict__ W, const float* __restrict__ bias,
    float* __restrict__ out, int N, int K, int k0)
{
    int tid = threadIdx.x;
    int w = tid >> 6, l = tid & 63;
    int i = l & 15, q = l >> 4;
    int n0 = blockIdx.x * 64 + w * 16;
    const float* wrow = W + (size_t)(n0 + i) * K + q * 8;
    const short8* bph = (const short8*)bhi + l;
    const short8* bpl = (const short8*)blo + l;

    floatx4 acc0 = {0.f, 0.f, 0.f, 0.f};
    floatx4 acc1 = {0.f, 0.f, 0.f, 0.f};

#pragma unroll 2
    for (int kk = k0; kk < k0 + KCHUNK; kk += 32) {
        float4 w0 = *(const float4*)(wrow + kk);
        float4 w1 = *(const float4*)(wrow + kk + 4);
        float wf[8] = {w0.x, w0.y, w0.z, w0.w, w1.x, w1.y, w1.z, w1.w};
        short8 ahi, alo;
#pragma unroll
        for (int j = 0; j < 8; ++j) {
            short hh = f2bf(wf[j]);
            ahi[j] = hh;
            if (SPLIT) alo[j] = f2bf(wf[j] - bf2f(hh));
        }
        int t2 = (kk >> 5) * 2;
        short8 b0 = bph[(size_t)t2 * 64];
        short8 b1 = bph[(size_t)(t2 + 1) * 64];
        acc0 = MFMA(ahi, b0, acc0);
        acc1 = MFMA(ahi, b1, acc1);
        if (SPLIT) {
            short8 l0 = bpl[(size_t)t2 * 64];
            short8 l1 = bpl[(size_t)(t2 + 1) * 64];
            acc0 = MFMA(ahi, l0, acc0);
            acc1 = MFMA(ahi, l1, acc1);
            acc0 = MFMA(alo, b0, acc0);
            acc1 = MFMA(alo, b1, acc1);
        }
    }

    __shared__ float lds[4][32][17];
#pragma unroll
    for (int r = 0; r < 4; ++r) {
        lds[w][i][q * 4 + r]      = acc0[r];   // lane holds D[m=q*4+r][n=i]
        lds[w][i + 16][q * 4 + r] = acc1[r];
    }
    __syncthreads();
    int b = l >> 1, hf = l & 1;
    float vo[8];
#pragma unroll
    for (int t = 0; t < 8; ++t) vo[t] = lds[w][b][hf * 8 + t];
    size_t obase = (size_t)b * N + n0 + hf * 8;
    if (ATOMIC) {
#pragma unroll
        for (int t = 0; t < 8; ++t) atomicAdd(out + obase + t, vo[t]);
    } else {
        const float4* bp4 = (const float4*)(bias + n0 + hf * 8);
        float4 bb0 = bp4[0], bb1 = bp4[1];
        float4 o0 = {vo[0] + bb0.x, vo[1] + bb0.y, vo[2] + bb0.z, vo[3] + bb0.w};
        float4 o1 = {vo[4] + bb1.x, vo[5] + bb1.y, vo[6] + bb1.z, vo[7] + bb1.w};
        float4* op = (float4*)(out + obase);
        op[0] = o0; op[1] = o1;
    }
}

// fused x-gates / h-gates (z picks which)
__global__ __launch_bounds__(256) void gemm_gates(
    const short* __restrict__ x0h, const short* __restrict__ x0l,
    const short* __restrict__ h0h, const short* __restrict__ h0l,
    const float* __restrict__ W_ih, const float* __restrict__ W_hh,
    float* __restrict__ xg, float* __restrict__ hg)
{
    if (blockIdx.z == 0)
        gemm_bt_body<1, 1, 512>(x0h, x0l, W_ih, nullptr, xg, 3072, 1024,
                                blockIdx.y * 512);
    else
        gemm_bt_body<1, 1, 512>(h0h, h0l, W_hh, nullptr, hg, 3072, 1024,
                                blockIdx.y * 512);
}

__global__ __launch_bounds__(256) void gemm_comb_k(
    const short* __restrict__ cath, const float* __restrict__ W_comb,
    float* __restrict__ comb)
{
    gemm_bt_body<1, 0, 256>(cath, nullptr, W_comb, nullptr, comb, 1024, 2048,
                            blockIdx.y * 256);
}

// ---------------------------------------------------------------------------
// GRU gate fusion -> dec, written as hi/lo swizzled bf16
// ---------------------------------------------------------------------------
__global__ __launch_bounds__(256) void gru_gate(
    const float* __restrict__ xg, const float* __restrict__ hg,
    const float* __restrict__ h0, short* __restrict__ dh, short* __restrict__ dl)
{
    int idx = blockIdx.x * 256 + threadIdx.x;   // 32*1024
    int b = idx >> 10, h = idx & 1023;
    const float* xp = xg + (size_t)b * 3072 + h;
    const float* hp = hg + (size_t)b * 3072 + h;
    float r = 1.f / (1.f + expf(-(xp[0] + hp[0])));
    float z = 1.f / (1.f + expf(-(xp[1024] + hp[1024])));
    float n = tanhf(xp[2048] + r * hp[2048]);
    float dec = (1.f - z) * n + z * h0[idx];
    short hh = f2bf(dec);
    size_t d = swz_idx(b, h);
    dh[d] = hh; dl[d] = f2bf(dec - bf2f(hh));
}

// ---------------------------------------------------------------------------
// v[b][e] += sum_k dec[b][k] * Wa[k][1024+e] : LDS-staged, coalesced We reads
// grid (E/64, K/128). A = dec (swizzled regs), B = We tile via LDS.
// ---------------------------------------------------------------------------
__global__ __launch_bounds__(256) void gemm_attn2(
    const short* __restrict__ dhi, const short* __restrict__ dlo,
    const float* __restrict__ Wa, float* __restrict__ v)
{
    int tid = threadIdx.x, w = tid >> 6, l = tid & 63;
    int i = l & 15, q = l >> 4;
    int e0 = blockIdx.x * 64;
    int k0 = blockIdx.y * 128;
    __shared__ float lds[32][65];

    const short8* ah = (const short8*)dhi;
    const short8* al = (const short8*)dlo;
    short8 Ah[4][2], Al[4][2];
#pragma unroll
    for (int t = 0; t < 4; ++t)
#pragma unroll
        for (int mt = 0; mt < 2; ++mt) {
            size_t idx = (size_t)((((k0 >> 5) + t) * 2 + mt) * 64) + l;
            Ah[t][mt] = ah[idx]; Al[t][mt] = al[idx];
        }

    floatx4 acc[2] = {{0.f,0.f,0.f,0.f},{0.f,0.f,0.f,0.f}};
    int sr = tid >> 3;          // 0..31 stage row
    int sc_ = (tid & 7) * 8;    // stage col
#pragma unroll
    for (int t = 0; t < 4; ++t) {
        const float* src = Wa + (size_t)(k0 + t * 32 + sr) * 2048 + 1024 + e0 + sc_;
        float4 s0 = *(const float4*)src;
        float4 s1 = *(const float4*)(src + 4);
        __syncthreads();
        *(float4*)&lds[sr][sc_]     = s0;
        *(float4*)&lds[sr][sc_ + 4] = s1;
        __syncthreads();
        short8 Bh, Bl;
#pragma unroll
        for (int j = 0; j < 8; ++j) {
            float f = lds[q * 8 + j][w * 16 + i];
            unsigned u = __builtin_bit_cast(unsigned, f);
            float hif = __builtin_bit_cast(float, u & 0xffff0000u);
            Bh[j] = (short)(u >> 16);
            float lo = f - hif;
            Bl[j] = (short)(__builtin_bit_cast(unsigned, lo) >> 16);
        }
        acc[0] = MFMA(Ah[t][0], Bh, acc[0]);
        acc[1] = MFMA(Ah[t][1], Bh, acc[1]);
        acc[0] = MFMA(Ah[t][0], Bl, acc[0]);
        acc[1] = MFMA(Ah[t][1], Bl, acc[1]);
        acc[0] = MFMA(Al[t][0], Bh, acc[0]);
        acc[1] = MFMA(Al[t][1], Bh, acc[1]);
    }
    // lane holds D[m = q*4+r (+16 for mt=1)][n = i]; m=b-offset, n=e-offset
#pragma unroll
    for (int mt = 0; mt < 2; ++mt)
#pragma unroll
        for (int r = 0; r < 4; ++r)
            atomicAdd(v + (size_t)(mt * 16 + q * 4 + r) * 1024 + e0 + w * 16 + i,
                      acc[mt][r]);
}

// ---------------------------------------------------------------------------
// scores[b][s] = v[b] . enc[s][b]
// ---------------------------------------------------------------------------
__global__ __launch_bounds__(256) void scores_k(
    const float* __restrict__ v, const float* __restrict__ enc,
    float* __restrict__ sc)
{
    int w = threadIdx.x >> 6, l = threadIdx.x & 63;
    int id = blockIdx.x * 4 + w;          // 0..4095
    int s = id >> 5, b = id & 31;
    const float4* ep = (const float4*)(enc + ((size_t)s * BDIM + b) * 1024);
    const float4* vp = (const float4*)(v + (size_t)b * 1024);
    float acc = 0.f;
#pragma unroll
    for (int c = 0; c < 4; ++c) {
        float4 e4 = ep[l + 64 * c];
        float4 v4 = vp[l + 64 * c];
        acc += e4.x * v4.x + e4.y * v4.y + e4.z * v4.z + e4.w * v4.w;
    }
    for (int o = 32; o; o >>= 1) acc += __shfl_down(acc, o);
    if (l == 0) sc[b * SD + s] = acc;
}

// ---------------------------------------------------------------------------
// fused softmax (redundant per block) + context + swizzled-bf16 cat write
// grid (4, 32): x = e-chunk of 256, y = b
// ---------------------------------------------------------------------------
__global__ __launch_bounds__(256) void ctx_softmax(
    const float* __restrict__ sc, const float* __restrict__ enc,
    short* __restrict__ cath, float* __restrict__ aw_out)
{
    int b = blockIdx.y, tid = threadIdx.x;
    int w = tid >> 6, l = tid & 63;
    __shared__ float a[SD];
    __shared__ float red[8];
    float x = (tid < SD) ? sc[b * SD + tid] : -3.4e38f;
    float m = x;
    for (int o = 32; o; o >>= 1) m = fmaxf(m, __shfl_down(m, o));
    if (l == 0) red[w] = m;
    __syncthreads();
    float M = fmaxf(fmaxf(red[0], red[1]), fmaxf(red[2], red[3]));
    float e = (tid < SD) ? __expf(x - M) : 0.f;
    float su = e;
    for (int o = 32; o; o >>= 1) su += __shfl_down(su, o);
    if (l == 0) red[4 + w] = su;
    __syncthreads();
    float S = red[4] + red[5] + red[6] + red[7];
    if (tid < SD) {
        float aw = e / S;
        a[tid] = aw;
        if (blockIdx.x == 0) aw_out[b * SD + tid] = aw;
    }
    __syncthreads();
    int ecol = blockIdx.x * 256 + tid;
    const float* p = enc + (size_t)b * 1024 + ecol;
    float acc = 0.f;
#pragma unroll 4
    for (int s = 0; s < SD; ++s) acc += a[s] * p[(size_t)s * (BDIM * 1024)];
    unsigned u = __builtin_bit_cast(unsigned, acc) + 0x8000u;
    cath[swz_idx(b, 1024 + ecol)] = (short)(u >> 16);
}

__global__ __launch_bounds__(256) void comb_prep(
    const float* __restrict__ comb, short* __restrict__ ch)
{
    int idx = blockIdx.x * 256 + threadIdx.x;   // 32*1024
    int b = idx >> 10, k = idx & 1023;
    ch[swz_idx(b, k)] = f2bf(comb[idx]);
}

// ---------------------------------------------------------------------------
// vocab GEMM: out[b][v] = comb[b].W_out[v] + b_out[v], plus per-b sum(exp)
// ---------------------------------------------------------------------------
__global__ __launch_bounds__(256) void gemm_out_k(
    const short* __restrict__ combh, const float* __restrict__ W,
    const float* __restrict__ bias, float* __restrict__ out,
    float* __restrict__ sexp)
{
    int tid = threadIdx.x, w = tid >> 6, l = tid & 63;
    int i = l & 15, q = l >> 4;
    int n0 = blockIdx.x * 64 + w * 16;
    const float* wrow = W + (size_t)(n0 + i) * 1024 + q * 8;
    const short8* bp = (const short8*)combh + l;
    floatx4 acc0 = {0.f, 0.f, 0.f, 0.f};
    floatx4 acc1 = {0.f, 0.f, 0.f, 0.f};
#pragma unroll 4
    for (int kk = 0; kk < 1024; kk += 32) {
        float4 w0 = *(const float4*)(wrow + kk);
        float4 w1 = *(const float4*)(wrow + kk + 4);
        union { unsigned u[4]; short8 s; } pk;
        pk.u[0] = pack2(w0.x, w0.y);
        pk.u[1] = pack2(w0.z, w0.w);
        pk.u[2] = pack2(w1.x, w1.y);
        pk.u[3] = pack2(w1.z, w1.w);
        int t2 = (kk >> 5) * 2;
        short8 b0 = bp[(size_t)t2 * 64];
        short8 b1 = bp[(size_t)(t2 + 1) * 64];
        acc0 = MFMA(pk.s, b0, acc0);
        acc1 = MFMA(pk.s, b1, acc1);
    }
    __shared__ float lds[4][32][17];
    __shared__ float bsum[32];
    if (tid < 32) bsum[tid] = 0.f;
#pragma unroll
    for (int r = 0; r < 4; ++r) {
        lds[w][i][q * 4 + r]      = acc0[r];
        lds[w][i + 16][q * 4 + r] = acc1[r];
    }
    __syncthreads();
    int b = l >> 1, hf = l & 1;
    float vo[8];
#pragma unroll
    for (int t = 0; t < 8; ++t) vo[t] = lds[w][b][hf * 8 + t];
    const float4* bp4 = (const float4*)(bias + n0 + hf * 8);
    float4 bb0 = bp4[0], bb1 = bp4[1];
    vo[0] += bb0.x; vo[1] += bb0.y; vo[2] += bb0.z; vo[3] += bb0.w;
    vo[4] += bb1.x; vo[5] += bb1.y; vo[6] += bb1.z; vo[7] += bb1.w;
    float es = 0.f;
#pragma unroll
    for (int t = 0; t < 8; ++t) es += __expf(vo[t]);
    atomicAdd(&bsum[b], es);
    float4 o0 = {vo[0], vo[1], vo[2], vo[3]};
    float4 o1 = {vo[4], vo[5], vo[6], vo[7]};
    float4* op = (float4*)(out + (size_t)b * VD + n0 + hf * 8);
    op[0] = o0; op[1] = o1;
    __syncthreads();
    if (tid < 32) atomicAdd(sexp + tid, bsum[tid]);
}

__global__ __launch_bounds__(256) void final_k(
    float* __restrict__ out, const float* __restrict__ sexp)
{
    int b = blockIdx.y;
    int vv = blockIdx.x * 256 + threadIdx.x;
    size_t o = (size_t)b * VD + vv;
    out[o] -= logf(sexp[b]);
}

// ---------------------------------------------------------------------------
extern "C" void kernel_launch(void* const* d_in, const int* in_sizes, int n_in,
                              void* d_out, int out_size, void* d_ws, size_t ws_size,
                              hipStream_t stream) {
    const float* x      = (const float*)d_in[0];
    const float* enc    = (const float*)d_in[1];
    const float* hid    = (const float*)d_in[2];
    const float* W_ih   = (const float*)d_in[3];
    const float* W_hh   = (const float*)d_in[4];
    const float* b_ih   = (const float*)d_in[5];
    const float* b_hh   = (const float*)d_in[6];
    const float* W_attn = (const float*)d_in[7];
    const float* W_comb = (const float*)d_in[9];
    const float* b_comb = (const float*)d_in[10];
    const float* W_out  = (const float*)d_in[11];
    const float* b_out  = (const float*)d_in[12];
    float* out = (float*)d_out;

    float* wsf   = (float*)d_ws;
    float* xg    = wsf;                  // 98304
    float* hg    = xg + 98304;           // 98304
    float* v     = hg + 98304;           // 32768
    float* sexp  = v + 32768;            // 32
    float* comb  = sexp + 32;            // 32768
    float* sc    = comb + 32768;         // 4096
    short* x0h   = (short*)(sc + 4096);
    short* x0l   = x0h + 32768;
    short* h0h   = x0l + 32768;
    short* h0l   = h0h + 32768;
    short* dh    = h0l + 32768;
    short* dl    = dh + 32768;
    short* cath  = dl + 32768;           // 65536
    short* combh = cath + 65536;         // 32768

    prep0<<<1281, 256, 0, stream>>>(x, hid, b_ih, b_hh, b_comb,
                                    xg, hg, v, sexp, comb,
                                    x0h, x0l, h0h, h0l, cath);
    gemm_gates<<<dim3(48, 2, 2), 256, 0, stream>>>(
        x0h, x0l, h0h, h0l, W_ih, W_hh, xg, hg);
    gru_gate<<<128, 256, 0, stream>>>(xg, hg, hid, dh, dl);
    gemm_attn2<<<dim3(16, 8), 256, 0, stream>>>(dh, dl, W_attn, v);
    scores_k<<<1024, 256, 0, stream>>>(v, enc, sc);
    ctx_softmax<<<dim3(4, 32), 256, 0, stream>>>(sc, enc, cath, out + 1024000);
    gemm_comb_k<<<dim3(16, 8), 256, 0, stream>>>(cath, W_comb, comb);
    comb_prep<<<128, 256, 0, stream>>>(comb, combh);
    gemm_out_k<<<500, 256, 0, stream>>>(combh, W_out, b_out, out, sexp);
    final_k<<<dim3(125, 32), 256, 0, stream>>>(out, sexp);
}